// Round 13
// baseline (1184.859 us; speedup 1.0000x reference)
//
#include <hip/hip_runtime.h>

// Liquid NN: BATCH=64, SEQ=256, IN=512, HID=1024, 2 layers, tau=0.5.
// h0(t) = h0 + a0*2*(tanh(x_t@W0^T + b0 + h0@U0^T) - h0)
// h1(t) = h1 + a1*2*(tanh(h0(t)@W1^T + b1 + h1@U1^T) - h1)
// Output: h1(255) as f32 (64,1024).
//
// R17 = R16 (fused Wx, 1033us) with the POST-DETECT CHAIN shortened:
//  (1) role1 TWO-PHASE: poll flag0>=t+1 -> h0 loads + W1*h0 MFMAs happen
//      BEFORE the binding flag1 poll. Safe: h0 slot t&7 can only be
//      overwritten by role0 step t+8, gated on flag1[*]>=t+1, which requires
//      THIS WG's step-t publish -> slot stable all through step t. flag0 is
//      ~7 steps early in steady state -> phase A poll is a single hot check.
//      Accumulation order (W1*h0 then U1*h1) identical to R16 -> bit-identical.
//  (2) red DOUBLE-BUFFERED (red[t&1], 2x17KB) -> the post-store __syncthreads
//      is gone; the only barrier left is the pre-reduce one.
//  (3) PER-WAVE flag words (64 per role per group): each wave publishes its
//      own word after `s_waitcnt vmcnt(0)` (the per-wave half of what
//      __syncthreads guaranteed; flag semantics = "this wave's share of the
//      slice is stored", union over 64 waves = full h state). Consumers poll
//      all 64 words with ONE 64-lane vector load (4 cache lines, 1 RTT).
//      Ring algebra per-wave: flag1w[j]>=s-7 <=> wave j finished step s-8 <=>
//      its h0(s-8) reads are done (reads precede its publish). Role1 poll
//      flag1[*]>=t covers peers' h1(t-1) AND h1-slot t&7 (needs only >=t-6).
// Substrate stays R15's VALIDATED one: relaxed AGENT atomic store publish /
// atomic load poll (R14's WGRP/sc0 L2-local scheme remains reverted).
//
// Kept (validated): 4 groups x 16 rows on 4 XCDs, 256-block grid (32/XCD
// pigeonhole election), depth-8 rings, no l1_inv (L1 capacity eviction:
// 64KB/step streamed through 32KB L1 -> 8-step-old lines long gone),
// fast exp tanh, 16-row XOR LDS reduce map @ stride 68, Wx fused into role0
// (x f32 loads pre-poll, L2-shared, b0 in f32).

typedef _Float16 f16;
typedef _Float16 f16x4 __attribute__((ext_vector_type(4)));
typedef _Float16 f16x8 __attribute__((ext_vector_type(8)));
typedef float    f32x4 __attribute__((ext_vector_type(4)));

#define B_  64
#define S_  256
#define IN_ 512
#define H_  1024
#define GR_ 16   // batch rows per group

static constexpr size_t OFF_H0R = 0;        // 4 groups x 8*16*H f16 = 1048576
static constexpr size_t OFF_H1R = 1048576;  // 4 groups x 8*16*H f16 = 1048576
static constexpr size_t OFF_FLG = 2097152;  // sync area (memset 32768 B)
// flg ints: group g (stride 256 ints = 1KB):
//   flag0w[64] @ g*256 (256B), flag1w[64] @ g*256+64 (next 256B)
//   word j = steps completed by wave j (= WGslice*4 + waveId) of that role
// election: ecnt[8] @ 1024, xgrp[8] @ 1032

#define AGENT __HIP_MEMORY_SCOPE_AGENT

// ---------------- persistent recurrent kernel (single kernel) ---------------
// 64-word flag poll, per-wave FULL condition: lane j waits f[j] >= tgt.
// One 64-lane vector load (4 cache lines) per round trip; publishes are plain
// relaxed AGENT stores (no RMW serialization).
__device__ __forceinline__ void pollf(const int* f, int tgt, int lane) {
  if (tgt <= 0) return;
  const int* p = f + lane;
  bool pend = true;
  if (__hip_atomic_load((int*)p, __ATOMIC_RELAXED, AGENT) >= tgt) pend = false;
  while (__ballot(pend)) {
    __builtin_amdgcn_s_sleep(1);
    if (pend && __hip_atomic_load((int*)p, __ATOMIC_RELAXED, AGENT) >= tgt)
      pend = false;
  }
}

// per-wave publish: drain THIS wave's vmem (h stores) then store its word.
__device__ __forceinline__ void publishw(int* word, int val, int lane) {
  asm volatile("s_waitcnt vmcnt(0)" ::: "memory");
  if (lane == 0) __hip_atomic_store(word, val, __ATOMIC_RELAXED, AGENT);
}

// fast tanh: t = e^{-2|x|} in (0,1], tanh = sign(x)*(1-t)/(1+t). ~1e-7 abs err.
__device__ __forceinline__ float fast_tanh(float x) {
  float t = __expf(-2.0f * fabsf(x));
  float r = (1.0f - t) / (1.0f + t);
  return copysignf(r, x);
}

// 16-row half-slab: M=16, 64 cols, K=256 per wave. ONE batch of 8 b128 loads
// (all in flight immediately) + 32 MFMA.
__device__ __forceinline__ void slab16(const f16* __restrict__ A, int kbase,
                                       int l15, int q,
                                       const f16x8 (&Bf)[4][8], f32x4 (&acc)[4]) {
  f16x8 cur[8];
  const f16* ar = A + (size_t)l15 * H_ + kbase + q * 8;
#pragma unroll
  for (int kf = 0; kf < 8; ++kf) cur[kf] = *(const f16x8*)(ar + kf * 32);
#pragma unroll
  for (int nt = 0; nt < 4; ++nt)
#pragma unroll
    for (int kf = 0; kf < 8; ++kf)
      acc[nt] = __builtin_amdgcn_mfma_f32_16x16x32_f16(cur[kf], Bf[nt][kf],
                                                       acc[nt], 0, 0, 0);
}

__global__ __launch_bounds__(256, 1) void k_persist(
    const float* __restrict__ x,  const float* __restrict__ W0,
    const float* __restrict__ U0, const float* __restrict__ b0,
    const float* __restrict__ W1, const float* __restrict__ U1,
    const float* __restrict__ alpha0, const float* __restrict__ alpha1,
    const float* __restrict__ b1,
    f16* h0r, f16* h1r, int* flg, float* out) {
  // red[buf][ks][i][col]: double-buffered (buf = step&1) so the post-store
  // barrier is gone. Stride 68 keeps the reduce-read bank-uniform.
  __shared__ __attribute__((aligned(16))) float red[2][4][16][68];  // 34 KiB
  const int tid = threadIdx.x;
  const int w = tid >> 6, lane = tid & 63;
  const int q = lane >> 4, l15 = lane & 15;

  int* ecnt = flg + 1024;  // per-XCD arrival tickets
  int* xgrp = flg + 1032;  // per-XCD group assignment: 0=pending, g+1, or -1

  // ---- election: 4 XCDs x 32 workers. 256 blocks = exactly 32/XCD resident
  // (validated); block 0 claims the first 4 full XCDs. AGENT scope (cross-XCD).
  const int xcc = (int)__builtin_amdgcn_s_getreg(6164) & 7;  // HW_REG_XCC_ID
  int* sh = (int*)&red[0][0][0][0];
  if (tid == 0) {
    int my = __hip_atomic_fetch_add(ecnt + xcc, 1, __ATOMIC_RELAXED, AGENT);
    if (blockIdx.x == 0) {
      unsigned taken = 0; int assigned = 0;
      while (assigned < 4) {
        for (int i = 0; i < 8 && assigned < 4; ++i)
          if (!((taken >> i) & 1) &&
              __hip_atomic_load(ecnt + i, __ATOMIC_RELAXED, AGENT) >= 32) {
            taken |= 1u << i;
            __hip_atomic_store(xgrp + i, assigned + 1, __ATOMIC_RELAXED, AGENT);
            ++assigned;
          }
        if (assigned < 4) __builtin_amdgcn_s_sleep(1);
      }
      for (int i = 0; i < 8; ++i)
        if (!((taken >> i) & 1))
          __hip_atomic_store(xgrp + i, -1, __ATOMIC_RELAXED, AGENT);
    }
    int grp = -1;
    if (my < 32) {
      int v;
      while ((v = __hip_atomic_load(xgrp + xcc, __ATOMIC_RELAXED, AGENT)) == 0)
        __builtin_amdgcn_s_sleep(1);
      if (v > 0) grp = v - 1;
    }
    sh[0] = (grp >= 0) ? my : -1;
    sh[1] = grp;
  }
  __syncthreads();
  const int myid = sh[0], g = sh[1];
  __syncthreads();
  if (myid < 0) return;
  const int role = myid >> 4, slice = myid & 15;
  const int c0 = slice * 64;
  const int kbase = w * 256;   // U-slab K-base (K=1024)
  const int kxbase = w * 128;  // W0-slab K-base (K=512), role0 only
  const int wword = slice * 4 + w;  // this wave's flag word index

  int* flag0w = flg + g * 256;       // word j = steps completed by role0 wave j
  int* flag1w = flg + g * 256 + 64;  // word j = steps completed by role1 wave j
  f16* h0g = h0r + (size_t)g * 8 * GR_ * H_;  // group's depth-8 rings
  f16* h1g = h1r + (size_t)g * 8 * GR_ * H_;

  // ---- weight slices into registers: B[k][n] = Wm[c][k] ----
  f16x8 BfA[4][8];  // role0: U0 ; role1: W1   (K=256/wave)
  f16x8 BfB[4][8];  // role1 only: U1          (K=256/wave)
  f16x8 BfX[4][4];  // role0 only: W0          (K=128/wave)
  {
    const float* WmA = (role == 0) ? U0 : W1;
#pragma unroll
    for (int nt = 0; nt < 4; ++nt)
#pragma unroll
      for (int kf = 0; kf < 8; ++kf) {
        const float* p = WmA + (size_t)(c0 + nt * 16 + l15) * H_ + kbase + kf * 32 + q * 8;
        f16x8 v;
#pragma unroll
        for (int j = 0; j < 8; ++j) v[j] = (f16)p[j];
        BfA[nt][kf] = v;
      }
    if (role == 1) {
#pragma unroll
      for (int nt = 0; nt < 4; ++nt)
#pragma unroll
        for (int kf = 0; kf < 8; ++kf) {
          const float* p = U1 + (size_t)(c0 + nt * 16 + l15) * H_ + kbase + kf * 32 + q * 8;
          f16x8 v;
#pragma unroll
          for (int j = 0; j < 8; ++j) v[j] = (f16)p[j];
          BfB[nt][kf] = v;
        }
    } else {
#pragma unroll
      for (int nt = 0; nt < 4; ++nt)
#pragma unroll
        for (int kf = 0; kf < 4; ++kf) {
          const float* p = W0 + (size_t)(c0 + nt * 16 + l15) * IN_ + kxbase + kf * 32 + q * 8;
          f16x8 v;
#pragma unroll
          for (int j = 0; j < 8; ++j) v[j] = (f16)p[j];
          BfX[nt][kf] = v;
        }
    }
  }

  // ---- epilogue ownership: thread owns (row16, 4 cols) — coalesced stores.
  const int row16 = tid >> 4, cgrp = tid & 15;
  const int iidx  = (cgrp >> 2) * 4 + (row16 & 3);
  const int bcol  = (row16 >> 2) * 16 + ((((cgrp & 3) * 4)) ^ ((row16 & 3) << 2));
  const int coff  = c0 + cgrp * 4;   // global col base of the 4 owned cols
  const int bglob = g * GR_ + row16; // global batch row

  float cf[4], bs[4];
  {
    const float* ap = ((role == 0) ? alpha0 : alpha1) + coff;
    const float* bp = ((role == 0) ? b0 : b1) + coff;
#pragma unroll
    for (int j = 0; j < 4; ++j) { cf[j] = ap[j] * 2.0f; bs[j] = bp[j]; }
  }

  float hst[4] = {0.f, 0.f, 0.f, 0.f};

  if (role == 0) {
    const float* xrow = x + ((size_t)(g * GR_ + l15) * S_) * IN_ + kxbase + q * 8;
    for (int s = 0; s < 256; ++s) {
      // x(s) loads issued BEFORE the polls (no dependency): in flight during
      // the detect; L2-shared across the 16 WGs.
      const float* xb = xrow + (size_t)s * IN_;
      float4 xv[4][2];
#pragma unroll
      for (int kf = 0; kf < 4; ++kf) {
        xv[kf][0] = *(const float4*)(xb + kf * 32);
        xv[kf][1] = *(const float4*)(xb + kf * 32 + 4);
      }
      f32x4 acc[4] = {};
      if (s > 0) {
        pollf(flag0w, s, lane);      // peers' h0(s-1) (binds)
        pollf(flag1w, s - 7, lane);  // h0 ring slot s&7 free (7-step slack)
        slab16(h0g + (size_t)((s - 1) & 7) * GR_ * H_, kbase, l15, q, BfA, acc);
      }
      // W0*x(s) into the SAME acc: K=128/wave.
      f16x8 ax[4];
#pragma unroll
      for (int kf = 0; kf < 4; ++kf) {
        f16x8 a;
        const float* v0 = (const float*)&xv[kf][0];
        const float* v1 = (const float*)&xv[kf][1];
#pragma unroll
        for (int j = 0; j < 4; ++j) { a[j] = (f16)v0[j]; a[4 + j] = (f16)v1[j]; }
        ax[kf] = a;
      }
#pragma unroll
      for (int nt = 0; nt < 4; ++nt)
#pragma unroll
        for (int kf = 0; kf < 4; ++kf)
          acc[nt] = __builtin_amdgcn_mfma_f32_16x16x32_f16(ax[kf], BfX[nt][kf],
                                                           acc[nt], 0, 0, 0);
      float (*rb)[16][68] = red[s & 1];
#pragma unroll
      for (int nt = 0; nt < 4; ++nt)
#pragma unroll
        for (int r = 0; r < 4; ++r)
          rb[w][nt * 4 + r][lane ^ (r << 2)] = acc[nt][r];
      __syncthreads();  // all waves' partials in red[s&1]
      f32x4 vs = {};
#pragma unroll
      for (int ks = 0; ks < 4; ++ks) {
        f32x4 v = *(const f32x4*)&rb[ks][iidx][bcol];
        vs[0] += v[0]; vs[1] += v[1]; vs[2] += v[2]; vs[3] += v[3];
      }
      f16* hw = h0g + (size_t)(s & 7) * GR_ * H_ + (size_t)row16 * H_ + coff;
      f16x4 o;
#pragma unroll
      for (int j = 0; j < 4; ++j) {
        float th = fast_tanh(vs[j] + bs[j]);
        float h = hst[j];
        h = h + cf[j] * (th - h);
        hst[j] = h;
        o[j] = (f16)h;
      }
      *(f16x4*)hw = o;
      // per-wave: drain own h stores, publish own word (no barrier: red is
      // double-buffered, so next step's LDS writes can't race slow readers).
      publishw(flag0w + wword, s + 1, lane);
    }
  } else {
    for (int t = 0; t < 256; ++t) {
      f32x4 acc[4] = {};
      // phase A (pre-detect): h0(t) slab. Slot t&7 is stable: its overwrite
      // (role0 step t+8) is gated on flag1[*]>=t+1 which needs OUR publish.
      pollf(flag0w, t + 1, lane);  // ~7 steps early in steady state
      slab16(h0g + (size_t)(t & 7) * GR_ * H_, kbase, l15, q, BfA, acc);
      if (t > 0) {
        // phase B (binding detect): peers' h1(t-1); also covers h1 ring.
        pollf(flag1w, t, lane);
        slab16(h1g + (size_t)((t - 1) & 7) * GR_ * H_, kbase, l15, q, BfB, acc);
      }
      float (*rb)[16][68] = red[t & 1];
#pragma unroll
      for (int nt = 0; nt < 4; ++nt)
#pragma unroll
        for (int r = 0; r < 4; ++r)
          rb[w][nt * 4 + r][lane ^ (r << 2)] = acc[nt][r];
      __syncthreads();  // all waves' partials in red[t&1]
      f32x4 vs = {};
#pragma unroll
      for (int ks = 0; ks < 4; ++ks) {
        f32x4 v = *(const f32x4*)&rb[ks][iidx][bcol];
        vs[0] += v[0]; vs[1] += v[1]; vs[2] += v[2]; vs[3] += v[3];
      }
      f16* hw = h1g + (size_t)(t & 7) * GR_ * H_ + (size_t)row16 * H_ + coff;
      f16x4 o;
#pragma unroll
      for (int j = 0; j < 4; ++j) {
        float th = fast_tanh(vs[j] + bs[j]);
        float h = hst[j];
        h = h + cf[j] * (th - h);
        hst[j] = h;
        o[j] = (f16)h;
      }
      *(f16x4*)hw = o;
      if (t == 255) {
        float* op = out + (size_t)bglob * H_ + coff;
        float4 vv;
        vv.x = hst[0]; vv.y = hst[1]; vv.z = hst[2]; vv.w = hst[3];
        *(float4*)op = vv;
      }
      publishw(flag1w + wword, t + 1, lane);
    }
  }
}

// LDS map identity (16-row variant): writer wave ks, lane = q*16+l15 stores
// D[m][n] (m=q*4+r, n=nt*16+l15) at red[b][ks][nt*4+r][(q*16+l15)^(r<<2)].
// Reader (row16,cgrp) wants (m=row16, n=cgrp*4+j): r=row16&3, nt=cgrp>>2,
// q=row16>>2, l15=(cgrp&3)*4+j -> i=nt*4+r, col'=q*16+(((cgrp&3)*4+j)^(r<<2)).
// XOR touches bits 2-3 only, j lives in bits 0-1 -> col' = bcol + j: one
// aligned f32x4 read. Bijective over 256 threads. Stride 68 -> bank-uniform.

extern "C" void kernel_launch(void* const* d_in, const int* in_sizes, int n_in,
                              void* d_out, int out_size, void* d_ws, size_t ws_size,
                              hipStream_t stream) {
  const float* x  = (const float*)d_in[0];
  const float* W0 = (const float*)d_in[1];
  const float* U0 = (const float*)d_in[2];
  const float* b0 = (const float*)d_in[3];
  const float* a0 = (const float*)d_in[4];
  const float* W1 = (const float*)d_in[5];
  const float* U1 = (const float*)d_in[6];
  const float* b1 = (const float*)d_in[7];
  const float* a1 = (const float*)d_in[8];
  char* ws = (char*)d_ws;
  f16*   h0r = (f16*)(ws + OFF_H0R);
  f16*   h1r = (f16*)(ws + OFF_H1R);
  int*   flg = (int*)(ws + OFF_FLG);
  float* out = (float*)d_out;

  hipMemsetAsync(flg, 0, 32768, stream);  // flags/election start at 0

  // Single persistent kernel. 256 blocks: exactly 32 resident per XCD
  // (validated); first 4 XCDs to fill claim groups 0-3; others exit.
  k_persist<<<256, 256, 0, stream>>>(x, W0, U0, b0, W1, U1, a0, a1, b1,
                                     h0r, h1r, flg, out);
}